// Round 1
// baseline (150.067 us; speedup 1.0000x reference)
//
#include <hip/hip_runtime.h>
#include <hip/hip_bf16.h>

// SGCN fused: y = conv1x1(x, W)+b ; out[n,c,t,w] = sum_{k,v} y[n,k,c,t,v]*A[k,v,w]
// x:[64,64,300,25] f32, A:[3,25,25] f32, W:[64,192] f32, b:[192] f32
// d_out = [out (64*64*300*25) ; A (1875)] f32

#define TT 6
#define TCHUNKS 50   // 300/TT
#define NB 64
#define CI 64
#define TDIM 300
#define VDIM 25
#define CO 64
#define KK 3

typedef __attribute__((ext_vector_type(8))) short bf16x8;
typedef __attribute__((ext_vector_type(4))) float f32x4;

// LDS regions (bytes)
#define XS_OFF 0        // [192 rows=(t*32+v)][64 i] bf16, 128B rows, swz ((row&7)<<4)
#define YS_OFF 24576    // [384 rows=(t*64+c)][32 v] bf16, 64B rows, swz ((row&3)<<4)
#define WK_OFF 49152    // [64 rows=c][64 i]  bf16, 128B rows, swz ((c&7)<<4)
#define AT_OFF 57344    // [3][32 rows=w][32 v] bf16, 64B rows, swz ((w&3)<<4)
#define SMEM_BYTES 63488

__device__ __forceinline__ unsigned short f2bf(float f) {
    unsigned int u = __builtin_bit_cast(unsigned int, f);
    u += 0x7fffu + ((u >> 16) & 1u);   // round-to-nearest-even
    return (unsigned short)(u >> 16);
}

__global__ __launch_bounds__(256, 2) void sgcn_fused(
    const float* __restrict__ x, const float* __restrict__ A,
    const float* __restrict__ W, const float* __restrict__ b,
    float* __restrict__ out)
{
    __shared__ __align__(16) char smem[SMEM_BYTES];
    const int tid  = threadIdx.x;
    const int lane = tid & 63;
    const int wid  = tid >> 6;
    const int n    = blockIdx.y;
    const int t0   = blockIdx.x * TT;

    // ---- stage xs: x[n, 2*i2(+1), t0+t, v] -> bf16 pair at xs[t*32+v][2*i2] ----
    for (int idx = tid; idx < 32 * TT * VDIM; idx += 256) {
        int i2 = idx / (TT * VDIM);
        int r  = idx % (TT * VDIM);
        int t  = r / VDIM;
        int v  = r % VDIM;
        const float* xp = x + (((size_t)n * CI + 2 * i2) * TDIM + (t0 + t)) * VDIM + v;
        float f0 = xp[0];
        float f1 = xp[(size_t)TDIM * VDIM];
        int row = t * 32 + v;
        int off = XS_OFF + row * 128 + ((4 * i2) ^ ((row & 7) << 4));
        unsigned int pk = (unsigned int)f2bf(f0) | ((unsigned int)f2bf(f1) << 16);
        *(unsigned int*)(smem + off) = pk;
    }
    // zero-pad rows v = 25..31
    for (int idx = tid; idx < TT * 7 * 32; idx += 256) {
        int i2 = idx & 31;
        int r  = idx >> 5;      // 0 .. TT*7-1
        int t  = r / 7;
        int pv = r % 7;
        int row = t * 32 + 25 + pv;
        int off = XS_OFF + row * 128 + ((4 * i2) ^ ((row & 7) << 4));
        *(unsigned int*)(smem + off) = 0u;
    }
    // ---- stage At: At[k][w][v] = bf16(A[k][v][w]), zero-padded to 32x32 ----
    for (int idx = tid; idx < 3 * 32 * 32; idx += 256) {
        int k    = idx >> 10;
        int r    = idx & 1023;
        int wrow = r >> 5;
        int v    = r & 31;
        unsigned short u = 0;
        if (wrow < VDIM && v < VDIM)
            u = f2bf(A[(k * VDIM + v) * VDIM + wrow]);
        int off = AT_OFF + k * 2048 + wrow * 64 + ((2 * v) ^ ((wrow & 3) << 4));
        *(unsigned short*)(smem + off) = u;
    }

    f32x4 acc2[6][2] = {};               // persistent stage2 accumulators
    const int i0 = (lane >> 4) * 8;      // k-dim element base within 32-chunk

    for (int k = 0; k < KK; ++k) {
        // ---- stage Wk[c][i] = bf16(W[i][k*64+c]) (pairs along i) ----
        for (int idx = tid; idx < 2048; idx += 256) {
            int i2 = idx >> 6;
            int c  = idx & 63;
            float f0 = W[(size_t)(2 * i2) * (KK * CO) + k * CO + c];
            float f1 = W[(size_t)(2 * i2 + 1) * (KK * CO) + k * CO + c];
            int off = WK_OFF + c * 128 + ((4 * i2) ^ ((c & 7) << 4));
            unsigned int pk = (unsigned int)f2bf(f0) | ((unsigned int)f2bf(f1) << 16);
            *(unsigned int*)(smem + off) = pk;
        }
        __syncthreads();

        // ---- stage1: D[(t,v)][c] = sum_i xs * Wk ; wave owns c-tile = wid ----
        {
            const int c = wid * 16 + (lane & 15);
            bf16x8 B0 = *(const bf16x8*)(smem + WK_OFF + c * 128 + ((2 * i0)      ^ ((c & 7) << 4)));
            bf16x8 B1 = *(const bf16x8*)(smem + WK_OFF + c * 128 + ((2 * i0 + 64) ^ ((c & 7) << 4)));
            float bv = b[k * CO + c];
            for (int m = 0; m < 12; ++m) {
                int j = m * 16 + (lane & 15);
                bf16x8 A0 = *(const bf16x8*)(smem + XS_OFF + j * 128 + ((2 * i0)      ^ ((j & 7) << 4)));
                bf16x8 A1 = *(const bf16x8*)(smem + XS_OFF + j * 128 + ((2 * i0 + 64) ^ ((j & 7) << 4)));
                f32x4 acc = {0.f, 0.f, 0.f, 0.f};
                acc = __builtin_amdgcn_mfma_f32_16x16x32_bf16(A0, B0, acc, 0, 0, 0);
                acc = __builtin_amdgcn_mfma_f32_16x16x32_bf16(A1, B1, acc, 0, 0, 0);
                // D rows j.. : t = m>>1, v = (m&1)*16 + (lane>>4)*4 + p
                int t   = m >> 1;
                int v0  = (m & 1) * 16 + (lane >> 4) * 4;
                int yrow = t * 64 + c;
                ushort4 pk;
                pk.x = f2bf(acc.x + bv); pk.y = f2bf(acc.y + bv);
                pk.z = f2bf(acc.z + bv); pk.w = f2bf(acc.w + bv);
                *(ushort4*)(smem + YS_OFF + yrow * 64 + ((2 * v0) ^ ((yrow & 3) << 4))) = pk;
            }
        }
        __syncthreads();

        // ---- stage2: acc2[(t,c)][w] += sum_v ys * At_k ----
        {
            bf16x8 Bf0, Bf1;
            {
                int wc0 = (lane & 15);
                int wc1 = 16 + (lane & 15);
                Bf0 = *(const bf16x8*)(smem + AT_OFF + k * 2048 + wc0 * 64 + ((2 * i0) ^ ((wc0 & 3) << 4)));
                Bf1 = *(const bf16x8*)(smem + AT_OFF + k * 2048 + wc1 * 64 + ((2 * i0) ^ ((wc1 & 3) << 4)));
            }
            for (int mi = 0; mi < 6; ++mi) {
                int ar = (wid * 6 + mi) * 16 + (lane & 15);
                bf16x8 Af = *(const bf16x8*)(smem + YS_OFF + ar * 64 + ((2 * i0) ^ ((ar & 3) << 4)));
                acc2[mi][0] = __builtin_amdgcn_mfma_f32_16x16x32_bf16(Af, Bf0, acc2[mi][0], 0, 0, 0);
                acc2[mi][1] = __builtin_amdgcn_mfma_f32_16x16x32_bf16(Af, Bf1, acc2[mi][1], 0, 0, 0);
            }
        }
        // Wk restage next iter only touches WK region (disjoint from ys/At) -> no barrier here
    }

    // ---- epilogue: acc2 tile rows = t*64+c, cols = w ----
    for (int mi = 0; mi < 6; ++mi) {
        int rt = (wid * 6 + mi) * 16;
        int t  = rt >> 6;
        int cb = (rt & 63) + (lane >> 4) * 4;
        for (int nt = 0; nt < 2; ++nt) {
            int wv = nt * 16 + (lane & 15);
            if (wv < VDIM) {
                f32x4 a = (nt == 0) ? acc2[mi][0] : acc2[mi][1];
                size_t base = (((size_t)n * CO + cb) * TDIM + (t0 + t)) * VDIM + wv;
                const size_t cs = (size_t)TDIM * VDIM;   // stride for c+1
                out[base]          = a.x;
                out[base + cs]     = a.y;
                out[base + 2 * cs] = a.z;
                out[base + 3 * cs] = a.w;
            }
        }
    }
}

__global__ void sgcn_acopy(const float* __restrict__ A, float* __restrict__ dst) {
    int i = blockIdx.x * blockDim.x + threadIdx.x;
    if (i < KK * VDIM * VDIM) dst[i] = A[i];
}

extern "C" void kernel_launch(void* const* d_in, const int* in_sizes, int n_in,
                              void* d_out, int out_size, void* d_ws, size_t ws_size,
                              hipStream_t stream) {
    const float* x = (const float*)d_in[0];
    const float* A = (const float*)d_in[1];
    const float* W = (const float*)d_in[2];
    const float* b = (const float*)d_in[3];
    float* out = (float*)d_out;

    dim3 grid(TCHUNKS, NB);
    sgcn_fused<<<grid, 256, 0, stream>>>(x, A, W, b, out);

    const size_t out_elems = (size_t)NB * CO * TDIM * VDIM;
    sgcn_acopy<<<(KK * VDIM * VDIM + 255) / 256, 256, 0, stream>>>(A, out + out_elems);
}

// Round 2
// 88.054 us; speedup vs baseline: 1.7043x; 1.7043x over previous
//
#include <hip/hip_runtime.h>
#include <hip/hip_bf16.h>

// SGCN fused: y = conv1x1(x, W)+b ; out[n,c,t,w] = sum_{k,v} y[n,k,c,t,v]*A[k,v,w]
// x:[64,64,300,25] f32, A:[3,25,25] f32, W:[64,192] f32, b:[192] f32
// d_out = [out (64*64*300*25) ; A (1875)] f32
//
// Round 2: W/A pre-converted to per-lane MFMA B-fragments in d_ws (prep kernel),
// ys stride 80B (conflict-free, no XOR), xs v-pad 28, LDS 52KB -> 3 blocks/CU.

#define TT 6
#define TCHUNKS 50
#define NB 64
#define CI 64
#define TDIM 300
#define VDIM 25
#define CO 64
#define KK 3

#define VP 28                 // padded v stride in xs
#define XROWS (TT*VP)         // 168 valid rows
#define XTILES 11             // 11*16 = 176 rows covered
#define XS_OFF 0              // [176 rows][128B] XOR swz ((r&7)<<4)  = 22528 B
#define YS_OFF 22528          // [384 rows=(t*64+c)][80B stride, 64B data] = 30720 B
#define SMEM_BYTES 53248      // 52 KB -> 3 blocks/CU

#define WBUF_BYTES (KK*4*2*64*16)   // 24576: [k][wave][half][lane] 16B frags
#define ABUF_BYTES (KK*2*64*16)     //  6144: [k][nt][lane] 16B frags

typedef __attribute__((ext_vector_type(8))) short bf16x8;
typedef __attribute__((ext_vector_type(4))) float f32x4;

__device__ __forceinline__ unsigned short f2bf(float f) {
    unsigned int u = __builtin_bit_cast(unsigned int, f);
    u += 0x7fffu + ((u >> 16) & 1u);   // round-to-nearest-even
    return (unsigned short)(u >> 16);
}

// ---- prep: build bf16 B-fragments for W and A in ws; copy A to out tail ----
__global__ void sgcn_prep(const float* __restrict__ A, const float* __restrict__ W,
                          unsigned int* __restrict__ wbuf, unsigned int* __restrict__ abuf,
                          float* __restrict__ outA) {
    int id = blockIdx.x * 256 + threadIdx.x;    // grid: 8*256 = 2048
    if (id < KK * 4 * 2 * 64) {                 // 1536 W-fragments
        int l  = id & 63;
        int h  = (id >> 6) & 1;
        int wq = (id >> 7) & 3;
        int k  = id >> 9;
        int c  = wq * 16 + (l & 15);
        int ib = (l >> 4) * 8 + h * 32;
        unsigned int pk[4];
        #pragma unroll
        for (int j = 0; j < 4; ++j) {
            unsigned short u0 = f2bf(W[(size_t)(ib + 2*j)     * (KK*CO) + k*CO + c]);
            unsigned short u1 = f2bf(W[(size_t)(ib + 2*j + 1) * (KK*CO) + k*CO + c]);
            pk[j] = (unsigned int)u0 | ((unsigned int)u1 << 16);
        }
        uint4* dst = (uint4*)(wbuf + id * 4);
        *dst = make_uint4(pk[0], pk[1], pk[2], pk[3]);
    }
    if (id < KK * 2 * 64) {                     // 384 A-fragments (At[w][v], zero-padded)
        int l  = id & 63;
        int nt = (id >> 6) & 1;
        int k  = id >> 7;
        int w  = nt * 16 + (l & 15);
        int vb = (l >> 4) * 8;
        unsigned int pk[4];
        #pragma unroll
        for (int j = 0; j < 4; ++j) {
            int v0 = vb + 2*j, v1 = vb + 2*j + 1;
            unsigned short u0 = (v0 < VDIM && w < VDIM) ? f2bf(A[k*VDIM*VDIM + v0*VDIM + w]) : (unsigned short)0;
            unsigned short u1 = (v1 < VDIM && w < VDIM) ? f2bf(A[k*VDIM*VDIM + v1*VDIM + w]) : (unsigned short)0;
            pk[j] = (unsigned int)u0 | ((unsigned int)u1 << 16);
        }
        uint4* dst = (uint4*)(abuf + id * 4);
        *dst = make_uint4(pk[0], pk[1], pk[2], pk[3]);
    }
    if (id < KK * VDIM * VDIM) outA[id] = A[id];   // output 1 of tuple (exact copy)
}

__global__ __launch_bounds__(256, 3) void sgcn_fused(
    const float* __restrict__ x, const float* __restrict__ b,
    const unsigned int* __restrict__ wbuf, const unsigned int* __restrict__ abuf,
    float* __restrict__ out)
{
    __shared__ __align__(16) char smem[SMEM_BYTES];
    const int tid  = threadIdx.x;
    const int lane = tid & 63;
    const int wid  = tid >> 6;
    const int n    = blockIdx.y;
    const int t0   = blockIdx.x * TT;
    const int i0   = (lane >> 4) * 8;       // K-chunk base within 32
    const int c    = wid * 16 + (lane & 15);

    // ---- load all B-fragments (L2-resident after first blocks) ----
    bf16x8 WB[KK][2], AB[KK][2];
    #pragma unroll
    for (int k = 0; k < KK; ++k) {
        #pragma unroll
        for (int h = 0; h < 2; ++h)
            WB[k][h] = *(const bf16x8*)(wbuf + (((k*4 + wid)*2 + h)*64 + lane)*4);
        #pragma unroll
        for (int nt = 0; nt < 2; ++nt)
            AB[k][nt] = *(const bf16x8*)(abuf + ((k*2 + nt)*64 + lane)*4);
    }
    float bv[KK];
    #pragma unroll
    for (int k = 0; k < KK; ++k) bv[k] = b[k*CO + c];

    // ---- stage xs: x[n, 2*i2(+1), t0+t, v] -> bf16 pair at xs[t*28+v][4*i2] ----
    for (int idx = tid; idx < 32 * XROWS; idx += 256) {   // 5376
        int i2 = idx / XROWS;
        int r  = idx - i2 * XROWS;
        int t  = r / VP;
        int v  = r - t * VP;
        float f0 = 0.f, f1 = 0.f;
        if (v < VDIM) {
            const float* xp = x + (((size_t)n * CI + 2*i2) * TDIM + (t0 + t)) * VDIM + v;
            f0 = xp[0];
            f1 = xp[(size_t)TDIM * VDIM];
        }
        int off = XS_OFF + r * 128 + ((4*i2) ^ ((r & 7) << 4));
        *(unsigned int*)(smem + off) = (unsigned int)f2bf(f0) | ((unsigned int)f2bf(f1) << 16);
    }
    // ---- zero ys pad columns v=28..31 (bytes 56..63) once ----
    for (int rr = tid; rr < 384; rr += 256)
        *(unsigned long long*)(smem + YS_OFF + rr * 80 + 56) = 0ULL;
    __syncthreads();

    f32x4 acc2[6][2] = {};

    #pragma unroll
    for (int k = 0; k < KK; ++k) {
        // ---- stage1: D[(t,v)][c] = sum_i xs*W ; write ys[t*64+c][v] ----
        #pragma unroll
        for (int m = 0; m < XTILES; ++m) {
            int j = m*16 + (lane & 15);
            bf16x8 A0 = *(const bf16x8*)(smem + XS_OFF + j*128 + ((2*i0)      ^ ((j & 7) << 4)));
            bf16x8 A1 = *(const bf16x8*)(smem + XS_OFF + j*128 + ((2*i0 + 64) ^ ((j & 7) << 4)));
            f32x4 acc = {0.f, 0.f, 0.f, 0.f};
            acc = __builtin_amdgcn_mfma_f32_16x16x32_bf16(A0, WB[k][0], acc, 0, 0, 0);
            acc = __builtin_amdgcn_mfma_f32_16x16x32_bf16(A1, WB[k][1], acc, 0, 0, 0);
            int r0 = m*16 + (lane >> 4) * 4;          // D rows r0..r0+3 (28%4==0: same t)
            if (r0 < XROWS) {
                int t  = r0 / VP;
                int v0 = r0 - t * VP;                 // in {0,4,...,24}
                int yrow = t * 64 + c;
                float bb = bv[k];
                ushort4 pk;
                pk.x = f2bf(acc.x + bb); pk.y = f2bf(acc.y + bb);
                pk.z = f2bf(acc.z + bb); pk.w = f2bf(acc.w + bb);
                *(ushort4*)(smem + YS_OFF + yrow * 80 + 2*v0) = pk;
            }
        }
        __syncthreads();
        // ---- stage2: acc2[(t,c)][w] += sum_v ys * At_k ----
        #pragma unroll
        for (int mi = 0; mi < 6; ++mi) {
            int ar = (wid*6 + mi)*16 + (lane & 15);
            bf16x8 Af = *(const bf16x8*)(smem + YS_OFF + ar * 80 + 2*i0);
            acc2[mi][0] = __builtin_amdgcn_mfma_f32_16x16x32_bf16(Af, AB[k][0], acc2[mi][0], 0, 0, 0);
            acc2[mi][1] = __builtin_amdgcn_mfma_f32_16x16x32_bf16(Af, AB[k][1], acc2[mi][1], 0, 0, 0);
        }
        if (k < KK-1) __syncthreads();
    }

    // ---- epilogue: acc2 rows = t*64+c, cols = w ----
    #pragma unroll
    for (int mi = 0; mi < 6; ++mi) {
        int rt = (wid*6 + mi) * 16;
        int t  = rt >> 6;
        int cb = (rt & 63) + (lane >> 4) * 4;
        #pragma unroll
        for (int nt = 0; nt < 2; ++nt) {
            int wv = nt*16 + (lane & 15);
            if (wv < VDIM) {
                f32x4 a = (nt == 0) ? acc2[mi][0] : acc2[mi][1];
                size_t base = (((size_t)n * CO + cb) * TDIM + (t0 + t)) * VDIM + wv;
                const size_t cs = (size_t)TDIM * VDIM;
                out[base]          = a.x;
                out[base + cs]     = a.y;
                out[base + 2*cs]   = a.z;
                out[base + 3*cs]   = a.w;
            }
        }
    }
}

extern "C" void kernel_launch(void* const* d_in, const int* in_sizes, int n_in,
                              void* d_out, int out_size, void* d_ws, size_t ws_size,
                              hipStream_t stream) {
    const float* x = (const float*)d_in[0];
    const float* A = (const float*)d_in[1];
    const float* W = (const float*)d_in[2];
    const float* b = (const float*)d_in[3];
    float* out = (float*)d_out;

    unsigned int* wbuf = (unsigned int*)d_ws;
    unsigned int* abuf = (unsigned int*)((char*)d_ws + WBUF_BYTES);

    const size_t out_elems = (size_t)NB * CO * TDIM * VDIM;
    sgcn_prep<<<8, 256, 0, stream>>>(A, W, wbuf, abuf, out + out_elems);

    dim3 grid(TCHUNKS, NB);
    sgcn_fused<<<grid, 256, 0, stream>>>(x, b, wbuf, abuf, out);
}